// Round 1
// baseline (492.286 us; speedup 1.0000x reference)
//
#include <hip/hip_runtime.h>

typedef _Float16 f16;
typedef __attribute__((ext_vector_type(8))) _Float16 half8;
typedef __attribute__((ext_vector_type(4))) float floatx4;
typedef unsigned int uint32;

#define MFMA16(a, b, c) __builtin_amdgcn_mfma_f32_16x16x32_f16((a), (b), (c), 0, 0, 0)

constexpr int B_ = 4, M_ = 1024, N_ = 4096, DQ_ = 512, DC_ = 512, H_ = 8, DH_ = 64, D_ = 512;

// ---------------- mask dtype detector ----------------
// Reads the first 16 MB (= whole buffer if bool-bytes, first quarter if int32).
// int32 masks hold only {0,1}; byte-layout bools make words with bits outside bit0.
__global__ __launch_bounds__(256) void detect_k(const uint32* __restrict__ w, uint32* __restrict__ flag) {
    int tid = blockIdx.x * 256 + threadIdx.x;
    bool bad = (w[tid] & 0xFFFFFFFEu) != 0u;
    unsigned long long any = __ballot(bad);
    if ((threadIdx.x & 63) == 0 && any) atomicOr(flag, 1u);
}

// ---------------- mask bit-pack (64 MB or 16 MB -> 2 MB) ----------------
__global__ __launch_bounds__(256) void pack_k(const void* __restrict__ mask,
                                              const uint32* __restrict__ flag,
                                              uint32* __restrict__ bits) {
    size_t tid = (size_t)blockIdx.x * 256 + threadIdx.x;
    bool pred;
    if (*flag)  // byte layout
        pred = ((const unsigned char*)mask)[tid] != 0;
    else        // int32 layout
        pred = ((const int*)mask)[tid] != 0;
    unsigned long long bal = __ballot(pred);
    int lane = threadIdx.x & 63;
    if (lane == 0)       bits[tid >> 5] = (uint32)bal;
    else if (lane == 32) bits[tid >> 5] = (uint32)(bal >> 32);
}

// ---------------- fp32 -> f16 cast ----------------
__global__ __launch_bounds__(256) void cast_k(const float* __restrict__ src, f16* __restrict__ dst) {
    int i = blockIdx.x * 256 + threadIdx.x;
    dst[i] = (f16)src[i];
}

// ---------------- fp32 (K=512, Nn) -> f16 transposed (Nn, 512) ----------------
__global__ __launch_bounds__(256) void tcast_k(const float* __restrict__ src, f16* __restrict__ dst, int Nn) {
    int i = blockIdx.x * 256 + threadIdx.x;  // i = n*512 + k
    int n = i >> 9, k = i & 511;
    dst[i] = (f16)src[(size_t)k * Nn + n];
}

// ---------------- generic 64x64-tile f16 MFMA GEMM: C = A @ Bt^T ----------------
// A: (Mr, K) row-major f16.  Bt: (Nr, K) row-major f16 (i.e., B transposed).
// MODE 0: C0 (Mr, Nr) f16.  MODE 1: col<512 -> Kout (Mr,512); col>=512 -> Vout (B,H,DH,N) transposed.
// MODE 2: Fout (Mr, Nr) f32 with bias[col].
template <int MODE>
__global__ __launch_bounds__(256)
void gemm_k(const f16* __restrict__ A, const f16* __restrict__ Bt, int K,
            f16* __restrict__ C0, f16* __restrict__ Kout, f16* __restrict__ Vout,
            float* __restrict__ Fout, const float* __restrict__ bias) {
    __shared__ __align__(16) f16 As[64][32];
    __shared__ __align__(16) f16 Bs[64][32];
    const int tid = threadIdx.x;
    const int lane = tid & 63, wave = tid >> 6;
    const int qd = lane >> 4, l16 = lane & 15;
    const int wm = wave >> 1, wn = wave & 1;
    const size_t m0 = (size_t)blockIdx.x * 64;
    const size_t n0 = (size_t)blockIdx.y * 64;
    const int Nr = gridDim.y * 64;
    const int lr = tid >> 2;
    const int lc = (tid & 3) * 8;

    floatx4 acc[2][2] = {};

    for (int k0 = 0; k0 < K; k0 += 32) {
        __syncthreads();
        *(uint4*)(&As[lr][lc]) = *(const uint4*)(A + (m0 + lr) * K + k0 + lc);
        *(uint4*)(&Bs[lr][lc]) = *(const uint4*)(Bt + (n0 + lr) * K + k0 + lc);
        __syncthreads();
        half8 a0 = *(const half8*)(&As[wm * 32 + l16][qd * 8]);
        half8 a1 = *(const half8*)(&As[wm * 32 + 16 + l16][qd * 8]);
        half8 b0 = *(const half8*)(&Bs[wn * 32 + l16][qd * 8]);
        half8 b1 = *(const half8*)(&Bs[wn * 32 + 16 + l16][qd * 8]);
        acc[0][0] = MFMA16(a0, b0, acc[0][0]);
        acc[0][1] = MFMA16(a0, b1, acc[0][1]);
        acc[1][0] = MFMA16(a1, b0, acc[1][0]);
        acc[1][1] = MFMA16(a1, b1, acc[1][1]);
    }

#pragma unroll
    for (int tm = 0; tm < 2; tm++)
#pragma unroll
        for (int tn = 0; tn < 2; tn++)
#pragma unroll
            for (int r = 0; r < 4; r++) {
                size_t row = m0 + wm * 32 + tm * 16 + qd * 4 + r;  // C/D: row = quad*4+reg
                size_t col = n0 + wn * 32 + tn * 16 + l16;         //      col = lane&15
                float v = acc[tm][tn][r];
                if constexpr (MODE == 0) {
                    C0[row * Nr + col] = (f16)v;
                } else if constexpr (MODE == 1) {
                    if (col < 512) {
                        Kout[row * 512 + col] = (f16)v;
                    } else {
                        int dcol = (int)col - 512;
                        int hh = dcol >> 6, dh = dcol & 63;
                        size_t bb = row >> 12, nn = row & 4095;  // rows = b*N + n, N=4096
                        Vout[((bb * H_ + hh) * (size_t)DH_ + dh) * N_ + nn] = (f16)v;
                    }
                } else {
                    Fout[row * Nr + col] = v + bias[col];
                }
            }
}

// ---------------- flash attention: one wave = 16 M-rows, loop N in 64-wide tiles ----------------
__global__ __launch_bounds__(256)
void attn_k(const f16* __restrict__ Qb, const f16* __restrict__ Kb,
            const f16* __restrict__ Vt, const uint32* __restrict__ mb,
            f16* __restrict__ Ob) {
    const int tid = threadIdx.x;
    const int lane = tid & 63, wave = tid >> 6;
    const int qd = lane >> 4, l16 = lane & 15;
    const int b = blockIdx.y >> 3, h = blockIdx.y & 7;
    const int m_base = blockIdx.x * 64 + wave * 16;

    __shared__ __align__(16) f16 psh[4][16][64];  // per-wave P tile for C-layout -> A-layout round trip

    // Q fragments (A-operand): Q[m=l16][k=qd*8+j], k in [0,64)
    const f16* qrow = Qb + ((size_t)(b * M_ + m_base + l16)) * D_ + h * DH_;
    half8 q0 = *(const half8*)(qrow + qd * 8);
    half8 q1 = *(const half8*)(qrow + 32 + qd * 8);

    floatx4 o[4] = {};        // [d-subtile s]; rows qd*4+r, col s*16+l16
    float mrun[4], lrun[4];   // per reg r -> row qd*4+r (replicated across the 16-lane quad)
#pragma unroll
    for (int r = 0; r < 4; r++) { mrun[r] = -3.0e38f; lrun[r] = 0.f; }

    const uint32* mrow[4];
#pragma unroll
    for (int r = 0; r < 4; r++)
        mrow[r] = mb + ((size_t)(b * M_ + m_base + qd * 4 + r)) * (N_ / 32);

    for (int n0 = 0; n0 < N_; n0 += 64) {
        // ---- S = Q K^T (per n-subtile s: 16 cols) ----
        floatx4 p[4];
#pragma unroll
        for (int s = 0; s < 4; s++) {
            const f16* krow = Kb + ((size_t)(b * N_ + n0 + s * 16 + l16)) * D_ + h * DH_;
            half8 k0 = *(const half8*)(krow + qd * 8);
            half8 k1 = *(const half8*)(krow + 32 + qd * 8);
            floatx4 t = {};
            t = MFMA16(q0, k0, t);
            t = MFMA16(q1, k1, t);
            p[s] = t;
        }
        // ---- mask + scale ----
        const int wi = n0 >> 5;
        float pv[4][4];
#pragma unroll
        for (int r = 0; r < 4; r++) {
            uint32 w0 = mrow[r][wi], w1 = mrow[r][wi + 1];
#pragma unroll
            for (int s = 0; s < 4; s++) {
                uint32 w = (s < 2) ? w0 : w1;
                int sh = (s * 16 + l16) & 31;
                pv[s][r] = ((w >> sh) & 1u) ? p[s][r] * 0.125f : -1.0e7f;
            }
        }
        // ---- online softmax (row = quad's 16 lanes x 4 subtiles) ----
        float alpha[4];
#pragma unroll
        for (int r = 0; r < 4; r++) {
            float tmax = fmaxf(fmaxf(pv[0][r], pv[1][r]), fmaxf(pv[2][r], pv[3][r]));
#pragma unroll
            for (int off = 1; off < 16; off <<= 1) tmax = fmaxf(tmax, __shfl_xor(tmax, off));
            float mn = fmaxf(mrun[r], tmax);
            alpha[r] = __expf(mrun[r] - mn);
            mrun[r] = mn;
            float rs = 0.f;
#pragma unroll
            for (int s = 0; s < 4; s++) { pv[s][r] = __expf(pv[s][r] - mn); rs += pv[s][r]; }
#pragma unroll
            for (int off = 1; off < 16; off <<= 1) rs += __shfl_xor(rs, off);
            lrun[r] = lrun[r] * alpha[r] + rs;
        }
#pragma unroll
        for (int s = 0; s < 4; s++)
#pragma unroll
            for (int r = 0; r < 4; r++) o[s][r] *= alpha[r];
        // ---- P: C-layout -> LDS -> A-layout (verified m120 pattern; wave-private region) ----
#pragma unroll
        for (int s = 0; s < 4; s++)
#pragma unroll
            for (int r = 0; r < 4; r++)
                psh[wave][qd * 4 + r][s * 16 + l16] = (f16)pv[s][r];
        half8 pa0 = *(const half8*)(&psh[wave][l16][qd * 8]);
        half8 pa1 = *(const half8*)(&psh[wave][l16][32 + qd * 8]);
        // ---- O += P V  (V transposed: contiguous-in-n loads) ----
#pragma unroll
        for (int s = 0; s < 4; s++) {
            const f16* vrow = Vt + ((size_t)((b * H_ + h) * DH_ + s * 16 + l16)) * N_ + n0;
            half8 v0 = *(const half8*)(vrow + qd * 8);
            half8 v1 = *(const half8*)(vrow + 32 + qd * 8);
            o[s] = MFMA16(pa0, v0, o[s]);
            o[s] = MFMA16(pa1, v1, o[s]);
        }
    }
    // ---- normalize + store O as (B*M, D) f16 ----
#pragma unroll
    for (int r = 0; r < 4; r++) {
        float inv = 1.0f / lrun[r];
        f16* orow = Ob + ((size_t)(b * M_ + m_base + qd * 4 + r)) * D_ + h * DH_;
#pragma unroll
        for (int s = 0; s < 4; s++) orow[s * 16 + l16] = (f16)(o[s][r] * inv);
    }
}

extern "C" void kernel_launch(void* const* d_in, const int* in_sizes, int n_in,
                              void* d_out, int out_size, void* d_ws, size_t ws_size,
                              hipStream_t stream) {
    const float* left  = (const float*)d_in[0];
    const float* right = (const float*)d_in[1];
    const void*  mask  = d_in[2];
    const float* Wq    = (const float*)d_in[3];
    const float* Wkv   = (const float*)d_in[4];
    const float* Wout  = (const float*)d_in[5];
    const float* bout  = (const float*)d_in[6];

    char* ws = (char*)d_ws;
    size_t off = 0;
    auto take = [&](size_t bytes) { char* p = ws + off; off += (bytes + 255) & ~(size_t)255; return p; };
    uint32* flag  = (uint32*)take(4);
    uint32* mbits = (uint32*)take((size_t)B_ * M_ * N_ / 8);       // 2 MB
    f16* leftb  = (f16*)take((size_t)B_ * M_ * DQ_ * 2);           // 4 MB
    f16* rightb = (f16*)take((size_t)B_ * N_ * DC_ * 2);           // 16 MB
    f16* wqt    = (f16*)take((size_t)DQ_ * D_ * 2);                // 0.5 MB
    f16* wkvt   = (f16*)take((size_t)DC_ * 2 * D_ * 2);            // 1 MB
    f16* woutt  = (f16*)take((size_t)D_ * DQ_ * 2);                // 0.5 MB
    f16* qb     = (f16*)take((size_t)B_ * M_ * D_ * 2);            // 4 MB
    f16* kb     = (f16*)take((size_t)B_ * N_ * D_ * 2);            // 16 MB
    f16* vt     = (f16*)take((size_t)B_ * H_ * DH_ * N_ * 2);      // 16 MB
    f16* ob     = (f16*)take((size_t)B_ * M_ * D_ * 2);            // 4 MB

    hipMemsetAsync(flag, 0, 4, stream);
    detect_k<<<16384, 256, 0, stream>>>((const uint32*)mask, flag);          // reads 16 MB (safe both layouts)
    pack_k<<<65536, 256, 0, stream>>>(mask, flag, mbits);                    // 16.7M mask elems
    cast_k<<<8192, 256, 0, stream>>>(left, leftb);                           // 2.1M
    cast_k<<<32768, 256, 0, stream>>>(right, rightb);                        // 8.4M
    tcast_k<<<1024, 256, 0, stream>>>(Wq, wqt, 512);
    tcast_k<<<2048, 256, 0, stream>>>(Wkv, wkvt, 1024);
    tcast_k<<<1024, 256, 0, stream>>>(Wout, woutt, 512);
    // Q = left @ Wq : (4096,512)@(512,512)
    gemm_k<0><<<dim3(64, 8), 256, 0, stream>>>(leftb, wqt, 512, qb, nullptr, nullptr, nullptr, nullptr);
    // KV = right @ Wkv : (16384,512)@(512,1024) -> K row-major, V transposed
    gemm_k<1><<<dim3(256, 16), 256, 0, stream>>>(rightb, wkvt, 512, nullptr, kb, vt, nullptr, nullptr);
    // fused masked flash attention
    attn_k<<<dim3(16, 32), 256, 0, stream>>>(qb, kb, vt, mbits, ob);
    // out = O @ Wout + bout : (4096,512)@(512,512) -> fp32
    gemm_k<2><<<dim3(64, 8), 256, 0, stream>>>(ob, woutt, 512, nullptr, nullptr, nullptr, (float*)d_out, bout);
}